// Round 11
// baseline (449.955 us; speedup 1.0000x reference)
//
#include <hip/hip_runtime.h>

#define B_ 2
#define S_ 2048
#define H_ 16
#define HD_ 128
#define QKVROW 6144   // 3*2048, row length of qkv activation
#define M_ 4096       // B_*S_

typedef float f32x4 __attribute__((ext_vector_type(4)));
typedef __bf16 bf16x8 __attribute__((ext_vector_type(8)));
typedef unsigned short ushortx8 __attribute__((ext_vector_type(8)));

__device__ __forceinline__ float bf2f(unsigned short u) {
  union { unsigned u; float f; } v;
  v.u = ((unsigned)u) << 16;
  return v.f;
}
__device__ __forceinline__ unsigned short f2bf(float f) {
  union { __bf16 b; unsigned short u; } c;
  c.b = (__bf16)f;  // native v_cvt path
  return c.u;
}
// 8 contiguous fp32 -> 8 bf16 ushorts (vector loads + native cvt)
__device__ __forceinline__ ushortx8 cvt8(const float* f) {
  const f32x4 lo = *(const f32x4*)f;
  const f32x4 hi = *(const f32x4*)(f + 4);
  ushortx8 o;
#pragma unroll
  for (int t = 0; t < 4; ++t) o[t] = f2bf(lo[t]);
#pragma unroll
  for (int t = 0; t < 4; ++t) o[4 + t] = f2bf(hi[t]);
  return o;
}
// async global->LDS, 16B/lane. LDS dest = wave-uniform base + lane*16.
__device__ __forceinline__ void async16(const unsigned short* g, unsigned short* l) {
  __builtin_amdgcn_global_load_lds(
      (const __attribute__((address_space(1))) unsigned int*)g,
      (__attribute__((address_space(3))) unsigned int*)l, 16, 0, 0);
}

// ---------------------------------------------------------------------------
// One-time fp32 -> bf16 conversion of x, Wqkv, wo PLUS RoPE cos/sin table.
// tab[s*128 + 2*j] = cos(s * base^(-j/64)), +1 = sin.
// ---------------------------------------------------------------------------
__global__ __launch_bounds__(256) void f2bf3t(
    const float* __restrict__ a, unsigned short* __restrict__ da, int na8,
    const float* __restrict__ b, unsigned short* __restrict__ db, int nb8,
    const float* __restrict__ c, unsigned short* __restrict__ dc, int nc8,
    float* __restrict__ tab, int nt8) {
  const int ntot = na8 + nb8 + nc8 + nt8;
  int i = blockIdx.x * 256 + threadIdx.x;
  const int stride = gridDim.x * 256;
  for (; i < ntot; i += stride) {
    int off = i;
    if (off < na8 + nb8 + nc8) {
      const float* s;
      unsigned short* d;
      if (off < na8) { s = a; d = da; }
      else if (off - na8 < nb8) { off -= na8; s = b; d = db; }
      else { off -= na8 + nb8; s = c; d = dc; }
      const ushortx8 o = cvt8(s + (size_t)off * 8);
      *(ushortx8*)&d[(size_t)off * 8] = o;
    } else {
      off -= na8 + nb8 + nc8;           // 8-float unit of tab
      float* dt = tab + (size_t)off * 8;
      const int e0 = off * 8;            // 128 floats per s-row; unit stays in-row
      const int s = e0 >> 7;
#pragma unroll
      for (int k = 0; k < 4; ++k) {
        const int j = ((e0 & 127) >> 1) + k;
        const float invf = expf(-(float)j * 0.14391156831212787f);  // ln(1e4)/64
        float sn, cs;
        sincosf((float)s * invf, &sn, &cs);
        dt[2 * k] = cs;
        dt[2 * k + 1] = sn;
      }
    }
  }
}

// ---------------------------------------------------------------------------
// GEMM1: qkv[m,n] = sum_k xb[m,k]*wb[n,k] + b[n].  xb,wb bf16; C bf16.
// m97 structure + rule-21 swizzle. Single 1536-block launch (no tail).
// ---------------------------------------------------------------------------
__global__ __launch_bounds__(256) void gemm1(
    const unsigned short* __restrict__ A, const unsigned short* __restrict__ Bm,
    const float* __restrict__ bias, unsigned short* __restrict__ C) {
  __shared__ unsigned short As[128 * 64];
  __shared__ unsigned short Bs[128 * 64];
  const int tid = threadIdx.x;
  const int lane = tid & 63, wave = tid >> 6;
  const int l15 = lane & 15, quad = lane >> 4;
  const int m0 = blockIdx.y * 128, n0 = blockIdx.x * 128;
  const int wr = (wave >> 1) * 64, wc = (wave & 1) * 64;

  f32x4 acc[4][4];
#pragma unroll
  for (int r = 0; r < 4; ++r)
#pragma unroll
    for (int c = 0; c < 4; ++c) acc[r][c] = (f32x4){0.f, 0.f, 0.f, 0.f};

  for (int k0 = 0; k0 < 2048; k0 += 64) {
    __syncthreads();  // prior iteration's frag reads done
#pragma unroll
    for (int i = 0; i < 4; ++i) {
      const int c0 = wave * 256 + i * 64;   // 16B-unit base within tile
      const int u = c0 + lane;
      const int row = u >> 3, cu = u & 7;   // 128 rows x 8 units
      const int cs = cu ^ (row & 7);        // pre-swizzled source column
      async16(A + (size_t)(m0 + row) * 2048 + k0 + cs * 8, &As[c0 * 8]);
      async16(Bm + (size_t)(n0 + row) * 2048 + k0 + cs * 8, &Bs[c0 * 8]);
    }
    __syncthreads();  // drains vmcnt -> tiles visible

#pragma unroll
    for (int s = 0; s < 2; ++s) {
      bf16x8 af[4], bf[4];
#pragma unroll
      for (int r = 0; r < 4; ++r) {
        const int row = wr + r * 16 + l15;
        af[r] = *(const bf16x8*)&As[row * 64 + (((s * 4 + quad) ^ (row & 7)) << 3)];
      }
#pragma unroll
      for (int c = 0; c < 4; ++c) {
        const int row = wc + c * 16 + l15;
        bf[c] = *(const bf16x8*)&Bs[row * 64 + (((s * 4 + quad) ^ (row & 7)) << 3)];
      }
#pragma unroll
      for (int r = 0; r < 4; ++r)
#pragma unroll
        for (int c = 0; c < 4; ++c)
          acc[r][c] = __builtin_amdgcn_mfma_f32_16x16x32_bf16(af[r], bf[c], acc[r][c], 0, 0, 0);
    }
  }

#pragma unroll
  for (int c = 0; c < 4; ++c) {
    const int col = n0 + wc + c * 16 + l15;
    const float bv = bias[col];
#pragma unroll
    for (int r = 0; r < 4; ++r) {
      const int row = m0 + wr + r * 16 + quad * 4;
#pragma unroll
      for (int i = 0; i < 4; ++i)
        C[(size_t)(row + i) * QKVROW + col] = f2bf(acc[r][c][i] + bv);
    }
  }
}

// ---------------------------------------------------------------------------
// In-place deinterleave+RoPE on q,k slots of qkv; Vt [b,h,hd,s] from v slot.
// q pre-scaled by hd^-0.5 * log2(e) so attn can use native exp2.
// ---------------------------------------------------------------------------
__global__ __launch_bounds__(256) void rope_vt(
    unsigned short* qkv, unsigned short* __restrict__ Vt,
    const float* __restrict__ tab) {
  __shared__ unsigned short vs[64 * 136];
  const int b = blockIdx.z, h = blockIdx.y, s0 = blockIdx.x * 64;
  const int tid = threadIdx.x;
  const int r = tid >> 2, cpart = (tid & 3) * 32;
  const int s = s0 + r;
  unsigned short* base = qkv + (size_t)(b * S_ + s) * QKVROW + h * 384;
  const int j0 = cpart >> 1;

  ushortx8 ivq[4], ivk[4], ivv[4];
#pragma unroll
  for (int i = 0; i < 4; ++i) {
    ivq[i] = *(const ushortx8*)&base[cpart + i * 8];
    ivk[i] = *(const ushortx8*)&base[128 + cpart + i * 8];
    ivv[i] = *(const ushortx8*)&base[256 + cpart + i * 8];
  }

  float cs[16], sn[16];
  {
    const f32x4* tr = (const f32x4*)&tab[(size_t)s * 128 + j0 * 2];
#pragma unroll
    for (int t = 0; t < 8; ++t) {
      const f32x4 v = tr[t];  // {cos,sin,cos,sin}
      cs[2 * t] = v[0]; sn[2 * t] = v[1];
      cs[2 * t + 1] = v[2]; sn[2 * t + 1] = v[3];
    }
  }

  __syncthreads();  // all reads of q/k rows done before anyone writes them

#pragma unroll
  for (int which = 0; which < 2; ++which) {
    const ushortx8* iv = (which == 0) ? ivq : ivk;
    // q: hd^-0.5 * log2(e)  (attn computes softmax with exp2)
    const float scale =
        (which == 0) ? (0.08838834764831845f * 1.4426950408889634f) : 1.0f;
    ushortx8 o1a, o1b, o2a, o2b;
#pragma unroll
    for (int t = 0; t < 16; ++t) {
      const float x1 = bf2f(iv[(2 * t) >> 3][(2 * t) & 7]);
      const float x2 = bf2f(iv[(2 * t + 1) >> 3][(2 * t + 1) & 7]);
      const unsigned short r1 = f2bf((x1 * cs[t] - x2 * sn[t]) * scale);
      const unsigned short r2 = f2bf((x2 * cs[t] + x1 * sn[t]) * scale);
      if (t < 8) { o1a[t] = r1; o2a[t] = r2; }
      else       { o1b[t - 8] = r1; o2b[t - 8] = r2; }
    }
    unsigned short* out = base + which * 128;
    *(ushortx8*)&out[j0] = o1a;
    *(ushortx8*)&out[j0 + 8] = o1b;
    *(ushortx8*)&out[64 + j0] = o2a;
    *(ushortx8*)&out[64 + j0 + 8] = o2b;
  }

#pragma unroll
  for (int i = 0; i < 4; ++i)
    *(ushortx8*)&vs[r * 136 + cpart + i * 8] = ivv[i];
  __syncthreads();
  const size_t vtb = (size_t)(b * H_ + h) * HD_ * S_ + s0;
#pragma unroll
  for (int it = 0; it < 4; ++it) {
    const int a = tid + it * 256;
    const int d = a >> 3, sc = (a & 7) * 8;
    ushortx8 o;
#pragma unroll
    for (int t = 0; t < 8; ++t) o[t] = vs[(sc + t) * 136 + d];
    *(ushortx8*)&Vt[vtb + (size_t)d * S_ + sc] = o;
  }
}

// ---------------------------------------------------------------------------
// Flash attention, causal. grid (32, 8, 2), 256 threads (4 waves).
// Round-11: TWO kv-64 tiles per barrier pair (double-buffered Ks/Vs, 72 KB,
// 2 blocks/CU) -- halves the ~35 barrier pairs/block that dominate this
// barrier-bound kernel (r9: MfmaUtil 15%, VALUBusy 36%, HBM 5%). Inner
// sub-tile body is the verified r10 code (swizzled LDS, exp2, defer-max,
// deferred-sum, setprio).
// ---------------------------------------------------------------------------
__global__ __launch_bounds__(256) void attn(
    unsigned short* qkv, const unsigned short* __restrict__ Vt) {
  __shared__ unsigned short Ks[2][64 * 128];  // 32 KB, swizzled
  __shared__ unsigned short Vs[2][128 * 64];  // 32 KB, swizzled
  __shared__ unsigned short Ps[4 * 16 * 64];  //  8 KB, swizzled per-wave strips
  const int bh = blockIdx.x, p = blockIdx.y, sub = blockIdx.z;
  const int b = bh >> 4, h = bh & 15;
  const int tid = threadIdx.x, lane = tid & 63, wave = tid >> 6;
  const int l15 = lane & 15, quad = lane >> 4;

  unsigned short* qh = qkv + (size_t)b * S_ * QKVROW + h * 384;
  const unsigned short* Vb = Vt + (size_t)bh * HD_ * S_;
  unsigned short* Pw = &Ps[wave * 16 * 64];

  ushortx8 rk[8], rv[8];
  auto pref = [&](int jp) {  // stage kv-64 tiles 2jp, 2jp+1 into regs
#pragma unroll
    for (int t = 0; t < 8; ++t) {
      const int tile = jp * 2 + (t >> 2);       // always valid memory (<= 31)
      const int uk = (t & 3) * 256 + tid;
      const int krow = uk >> 4, kcu = uk & 15;  // 64 rows x 16 units
      rk[t] = *(const ushortx8*)(qh + (size_t)(tile * 64 + krow) * QKVROW + 128 + kcu * 8);
      const int vrow = uk >> 3, vcu = uk & 7;   // 128 rows x 8 units
      rv[t] = *(const ushortx8*)(Vb + (size_t)vrow * S_ + tile * 64 + vcu * 8);
    }
  };
  pref(0);

#pragma unroll
  for (int half = 0; half < 2; ++half) {
    const int qt = half ? 15 - p : p;   // short tile first, then long
    const int jN = 2 * qt + 1 + sub;    // kv-64 tiles needed for this half-tile
    const int jP = (jN + 1) >> 1;       // kv-128 barrier pairs
    const int r0 = qt * 128 + sub * 64 + wave * 16;  // first q-row of this wave

    bf16x8 aq[4];
#pragma unroll
    for (int ks = 0; ks < 4; ++ks)
      aq[ks] = *(const bf16x8*)&qh[(size_t)(r0 + l15) * QKVROW + ks * 32 + quad * 8];

    f32x4 o[8];
    float mrow[4], lpart[4];
#pragma unroll
    for (int ct = 0; ct < 8; ++ct) o[ct] = (f32x4){0.f, 0.f, 0.f, 0.f};
#pragma unroll
    for (int i = 0; i < 4; ++i) { mrow[i] = -1e30f; lpart[i] = 0.f; }

    for (int jp = 0; jp < jP; ++jp) {
      __syncthreads();  // all waves done reading both buffers of prior pair
#pragma unroll
      for (int t = 0; t < 8; ++t) {
        const int buf = t >> 2;
        const int uk = (t & 3) * 256 + tid;
        const int krow = uk >> 4, kun = uk & 15;
        *(ushortx8*)&Ks[buf][krow * 128 + ((kun ^ (krow & 7)) << 3)] = rk[t];
        const int vrow = uk >> 3, vun = uk & 7;
        *(ushortx8*)&Vs[buf][vrow * 64 + ((vun ^ (vrow & 7)) << 3)] = rv[t];
      }
      __syncthreads();  // both tiles visible

      const int jpn = (jp + 1 < jP) ? jp + 1 : (half == 0 ? 0 : -1);
      if (jpn >= 0) pref(jpn);  // overlaps compute below

#pragma unroll
      for (int ht = 0; ht < 2; ++ht) {
        const int j2 = jp * 2 + ht;     // kv-64 index
        if (j2 >= jN) continue;         // block-uniform guard (odd-jN tail)

        // S = Q K^T over this kv-64 tile (Q pre-scaled by hd^-0.5*log2e)
        f32x4 sacc[4];
#pragma unroll
        for (int ct = 0; ct < 4; ++ct) sacc[ct] = (f32x4){0.f, 0.f, 0.f, 0.f};
        __builtin_amdgcn_s_setprio(1);
#pragma unroll
        for (int ks = 0; ks < 4; ++ks) {
          bf16x8 bk[4];
#pragma unroll
          for (int ct = 0; ct < 4; ++ct)
            bk[ct] = *(const bf16x8*)&Ks[ht][(ct * 16 + l15) * 128 +
                                            (((ks * 4 + quad) ^ (l15 & 7)) << 3)];
#pragma unroll
          for (int ct = 0; ct < 4; ++ct)
            sacc[ct] = __builtin_amdgcn_mfma_f32_16x16x32_bf16(aq[ks], bk[ct], sacc[ct], 0, 0, 0);
        }
        __builtin_amdgcn_s_setprio(0);

        if (j2 >= 2 * qt) {  // diagonal region: mask gcol > grow
#pragma unroll
          for (int ct = 0; ct < 4; ++ct)
#pragma unroll
            for (int i = 0; i < 4; ++i) {
              const int grow = r0 + quad * 4 + i;
              const int gcol = j2 * 64 + ct * 16 + l15;
              if (gcol > grow) sacc[ct][i] = -1e30f;
            }
        }

        // per-row tile max (uniform within each 16-lane row group)
        float tmax[4];
#pragma unroll
        for (int i = 0; i < 4; ++i) {
          float m = fmaxf(fmaxf(sacc[0][i], sacc[1][i]), fmaxf(sacc[2][i], sacc[3][i]));
#pragma unroll
          for (int off = 1; off < 16; off <<= 1) m = fmaxf(m, __shfl_xor(m, off));
          tmax[i] = m;
        }
        // defer-max: rescale only when some row's max grew past THR=8 (log2)
        bool need = false;
#pragma unroll
        for (int i = 0; i < 4; ++i) need = need || (tmax[i] > mrow[i] + 8.f);
        if (__any(need)) {
#pragma unroll
          for (int i = 0; i < 4; ++i) {
            const float mn = fmaxf(mrow[i], tmax[i]);
            const float alpha = exp2f(mrow[i] - mn);
            mrow[i] = mn;
            lpart[i] *= alpha;
#pragma unroll
            for (int ct = 0; ct < 8; ++ct) o[ct][i] *= alpha;
          }
        }
        // P = exp2(S - mrow); accumulate per-lane partial row sums
#pragma unroll
        for (int i = 0; i < 4; ++i) {
          float rs = 0.f;
#pragma unroll
          for (int ct = 0; ct < 4; ++ct) {
            const float pv = exp2f(sacc[ct][i] - mrow[i]);
            sacc[ct][i] = pv;
            rs += pv;
          }
          lpart[i] += rs;
        }

        // P into wave-private swizzled strip (C-layout -> A-layout)
#pragma unroll
        for (int ct = 0; ct < 4; ++ct)
#pragma unroll
          for (int i = 0; i < 4; ++i) {
            const int row = quad * 4 + i;
            const int u = ct * 2 + (l15 >> 3);
            Pw[row * 64 + ((u ^ (row & 7)) << 3) + (l15 & 7)] = f2bf(sacc[ct][i]);
          }

        // O += P * V
        __builtin_amdgcn_s_setprio(1);
#pragma unroll
        for (int ks = 0; ks < 2; ++ks) {
          const bf16x8 ap = *(const bf16x8*)&Pw[l15 * 64 +
                                                (((ks * 4 + quad) ^ (l15 & 7)) << 3)];
          bf16x8 bv[8];
#pragma unroll
          for (int ct = 0; ct < 8; ++ct)
            bv[ct] = *(const bf16x8*)&Vs[ht][(ct * 16 + l15) * 64 +
                                             (((ks * 4 + quad) ^ (l15 & 7)) << 3)];
#pragma unroll
          for (int ct = 0; ct < 8; ++ct)
            o[ct] = __builtin_amdgcn_mfma_f32_16x16x32_bf16(ap, bv[ct], o[ct], 0, 0, 0);
        }
        __builtin_amdgcn_s_setprio(0);
      }
    }

    // final 16-lane sum reduction (once per q-tile), then write ctx
    float inv[4];
#pragma unroll
    for (int i = 0; i < 4; ++i) {
      float l = lpart[i];
#pragma unroll
      for (int off = 1; off < 16; off <<= 1) l += __shfl_xor(l, off);
      inv[i] = 1.0f / l;
    }
#pragma unroll
    for (int ct = 0; ct < 8; ++ct)
#pragma unroll
      for (int i = 0; i < 4; ++i) {
        const int srow = r0 + quad * 4 + i;
        qh[(size_t)srow * QKVROW + ct * 16 + l15] = f2bf(o[ct][i] * inv[i]);
      }
  }
}

// ---------------------------------------------------------------------------
// GEMM2: out[m,n] = sum_k ctx[m,k]*wob[n,k] + bo[n].  Both operands bf16,
// both staged via global_load_lds with rule-21 swizzle. (Verified.)
// ---------------------------------------------------------------------------
__global__ __launch_bounds__(256) void gemm2(
    const unsigned short* __restrict__ A, const unsigned short* __restrict__ Bm,
    const float* __restrict__ bias, float* __restrict__ C) {
  __shared__ unsigned short As[128 * 64];
  __shared__ unsigned short Bs[128 * 64];
  const int tid = threadIdx.x;
  const int lane = tid & 63, wave = tid >> 6;
  const int l15 = lane & 15, quad = lane >> 4;
  const int m0 = blockIdx.y * 128, n0 = blockIdx.x * 128;
  const int wr = (wave >> 1) * 64, wc = (wave & 1) * 64;

  f32x4 acc[4][4];
#pragma unroll
  for (int r = 0; r < 4; ++r)
#pragma unroll
    for (int c = 0; c < 4; ++c) acc[r][c] = (f32x4){0.f, 0.f, 0.f, 0.f};

  for (int k0 = 0; k0 < 2048; k0 += 64) {
    const int kh = ((k0 >> 7) * 384) + (k0 & 127);  // ctx lives in q slots
    __syncthreads();  // prior frag reads done
#pragma unroll
    for (int i = 0; i < 4; ++i) {
      const int c0 = wave * 256 + i * 64;
      const int u = c0 + lane;
      const int row = u >> 3, cu = u & 7;
      const int cs = cu ^ (row & 7);        // pre-swizzled source column
      async16(A + (size_t)(m0 + row) * QKVROW + kh + cs * 8, &As[c0 * 8]);
      async16(Bm + (size_t)(n0 + row) * 2048 + k0 + cs * 8, &Bs[c0 * 8]);
    }
    __syncthreads();  // drains vmcnt -> tiles visible

#pragma unroll
    for (int s = 0; s < 2; ++s) {
      bf16x8 af[4], bf[4];
#pragma unroll
      for (int r = 0; r < 4; ++r) {
        const int row = wr + r * 16 + l15;
        af[r] = *(const bf16x8*)&As[row * 64 + (((s * 4 + quad) ^ (row & 7)) << 3)];
      }
#pragma unroll
      for (int c = 0; c < 4; ++c) {
        const int row = wc + c * 16 + l15;
        bf[c] = *(const bf16x8*)&Bs[row * 64 + (((s * 4 + quad) ^ (row & 7)) << 3)];
      }
#pragma unroll
      for (int r = 0; r < 4; ++r)
#pragma unroll
        for (int c = 0; c < 4; ++c)
          acc[r][c] = __builtin_amdgcn_mfma_f32_16x16x32_bf16(af[r], bf[c], acc[r][c], 0, 0, 0);
    }
  }

#pragma unroll
  for (int c = 0; c < 4; ++c) {
    const int col = n0 + wc + c * 16 + l15;
    const float bv = bias[col];
#pragma unroll
    for (int r = 0; r < 4; ++r) {
      const int row = m0 + wr + r * 16 + quad * 4;
#pragma unroll
      for (int i = 0; i < 4; ++i)
        C[(size_t)(row + i) * 2048 + col] = acc[r][c][i] + bv;
    }
  }
}

extern "C" void kernel_launch(void* const* d_in, const int* in_sizes, int n_in,
                              void* d_out, int out_size, void* d_ws, size_t ws_size,
                              hipStream_t stream) {
  const float* x    = (const float*)d_in[0];
  const float* wqkv = (const float*)d_in[1];
  const float* bqkv = (const float*)d_in[2];
  const float* wo   = (const float*)d_in[3];
  const float* bo   = (const float*)d_in[4];
  float* out = (float*)d_out;

  unsigned short* qkv = (unsigned short*)d_ws;            // 50.3 MB [4096][6144]
  unsigned short* Vt  = qkv + (size_t)M_ * QKVROW;        // 16.8 MB [b,h,hd,s]
  unsigned short* xb  = Vt  + (size_t)B_ * H_ * HD_ * S_; // 16.8 MB [4096][2048] bf16
  unsigned short* wb  = xb  + (size_t)M_ * 2048;          // 25.2 MB [6144][2048] bf16
  unsigned short* wob = wb  + (size_t)QKVROW * 2048;      //  8.4 MB [2048][2048] bf16
  float* tab = (float*)(wob + (size_t)2048 * 2048);       //  1.0 MB [2048][64][2]

  f2bf3t<<<dim3(2048), 256, 0, stream>>>(x, xb, (M_ * 2048) / 8,
                                         wqkv, wb, (QKVROW * 2048) / 8,
                                         wo, wob, (2048 * 2048) / 8,
                                         tab, (S_ * 128) / 8);

  gemm1<<<dim3(QKVROW / 128, M_ / 128), 256, 0, stream>>>(xb, wb, bqkv, qkv);
  rope_vt<<<dim3(S_ / 64, H_, B_), 256, 0, stream>>>(qkv, Vt, tab);
  attn<<<dim3(B_ * H_, 8, 2), 256, 0, stream>>>(qkv, Vt);
  gemm2<<<dim3(2048 / 128, M_ / 128), 256, 0, stream>>>(qkv, wob, bo, out);
}

// Round 12
// 408.632 us; speedup vs baseline: 1.1011x; 1.1011x over previous
//
#include <hip/hip_runtime.h>

#define B_ 2
#define S_ 2048
#define H_ 16
#define HD_ 128
#define QKVROW 6144   // 3*2048, row length of qkv activation
#define M_ 4096       // B_*S_

typedef float f32x4 __attribute__((ext_vector_type(4)));
typedef __bf16 bf16x8 __attribute__((ext_vector_type(8)));
typedef unsigned short ushortx8 __attribute__((ext_vector_type(8)));

__device__ __forceinline__ float bf2f(unsigned short u) {
  union { unsigned u; float f; } v;
  v.u = ((unsigned)u) << 16;
  return v.f;
}
__device__ __forceinline__ unsigned short f2bf(float f) {
  union { __bf16 b; unsigned short u; } c;
  c.b = (__bf16)f;  // native v_cvt path
  return c.u;
}
// 8 contiguous fp32 -> 8 bf16 ushorts (vector loads + native cvt)
__device__ __forceinline__ ushortx8 cvt8(const float* f) {
  const f32x4 lo = *(const f32x4*)f;
  const f32x4 hi = *(const f32x4*)(f + 4);
  ushortx8 o;
#pragma unroll
  for (int t = 0; t < 4; ++t) o[t] = f2bf(lo[t]);
#pragma unroll
  for (int t = 0; t < 4; ++t) o[4 + t] = f2bf(hi[t]);
  return o;
}
// async global->LDS, 16B/lane. LDS dest = wave-uniform base + lane*16.
__device__ __forceinline__ void async16(const unsigned short* g, unsigned short* l) {
  __builtin_amdgcn_global_load_lds(
      (const __attribute__((address_space(1))) unsigned int*)g,
      (__attribute__((address_space(3))) unsigned int*)l, 16, 0, 0);
}

// ---------------------------------------------------------------------------
// One-time fp32 -> bf16 conversion of x, Wqkv, wo PLUS RoPE cos/sin table.
// tab[s*128 + 2*j] = cos(s * base^(-j/64)), +1 = sin.
// ---------------------------------------------------------------------------
__global__ __launch_bounds__(256) void f2bf3t(
    const float* __restrict__ a, unsigned short* __restrict__ da, int na8,
    const float* __restrict__ b, unsigned short* __restrict__ db, int nb8,
    const float* __restrict__ c, unsigned short* __restrict__ dc, int nc8,
    float* __restrict__ tab, int nt8) {
  const int ntot = na8 + nb8 + nc8 + nt8;
  int i = blockIdx.x * 256 + threadIdx.x;
  const int stride = gridDim.x * 256;
  for (; i < ntot; i += stride) {
    int off = i;
    if (off < na8 + nb8 + nc8) {
      const float* s;
      unsigned short* d;
      if (off < na8) { s = a; d = da; }
      else if (off - na8 < nb8) { off -= na8; s = b; d = db; }
      else { off -= na8 + nb8; s = c; d = dc; }
      const ushortx8 o = cvt8(s + (size_t)off * 8);
      *(ushortx8*)&d[(size_t)off * 8] = o;
    } else {
      off -= na8 + nb8 + nc8;           // 8-float unit of tab
      float* dt = tab + (size_t)off * 8;
      const int e0 = off * 8;            // 128 floats per s-row; unit stays in-row
      const int s = e0 >> 7;
#pragma unroll
      for (int k = 0; k < 4; ++k) {
        const int j = ((e0 & 127) >> 1) + k;
        const float invf = expf(-(float)j * 0.14391156831212787f);  // ln(1e4)/64
        float sn, cs;
        sincosf((float)s * invf, &sn, &cs);
        dt[2 * k] = cs;
        dt[2 * k + 1] = sn;
      }
    }
  }
}

// ---------------------------------------------------------------------------
// GEMM1: qkv[m,n] = sum_k xb[m,k]*wb[n,k] + b[n].  xb,wb bf16; C bf16.
// m97 structure + rule-21 swizzle. Single 1536-block launch (no tail).
// ---------------------------------------------------------------------------
__global__ __launch_bounds__(256) void gemm1(
    const unsigned short* __restrict__ A, const unsigned short* __restrict__ Bm,
    const float* __restrict__ bias, unsigned short* __restrict__ C) {
  __shared__ unsigned short As[128 * 64];
  __shared__ unsigned short Bs[128 * 64];
  const int tid = threadIdx.x;
  const int lane = tid & 63, wave = tid >> 6;
  const int l15 = lane & 15, quad = lane >> 4;
  const int m0 = blockIdx.y * 128, n0 = blockIdx.x * 128;
  const int wr = (wave >> 1) * 64, wc = (wave & 1) * 64;

  f32x4 acc[4][4];
#pragma unroll
  for (int r = 0; r < 4; ++r)
#pragma unroll
    for (int c = 0; c < 4; ++c) acc[r][c] = (f32x4){0.f, 0.f, 0.f, 0.f};

  for (int k0 = 0; k0 < 2048; k0 += 64) {
    __syncthreads();  // prior iteration's frag reads done
#pragma unroll
    for (int i = 0; i < 4; ++i) {
      const int c0 = wave * 256 + i * 64;   // 16B-unit base within tile
      const int u = c0 + lane;
      const int row = u >> 3, cu = u & 7;   // 128 rows x 8 units
      const int cs = cu ^ (row & 7);        // pre-swizzled source column
      async16(A + (size_t)(m0 + row) * 2048 + k0 + cs * 8, &As[c0 * 8]);
      async16(Bm + (size_t)(n0 + row) * 2048 + k0 + cs * 8, &Bs[c0 * 8]);
    }
    __syncthreads();  // drains vmcnt -> tiles visible

#pragma unroll
    for (int s = 0; s < 2; ++s) {
      bf16x8 af[4], bf[4];
#pragma unroll
      for (int r = 0; r < 4; ++r) {
        const int row = wr + r * 16 + l15;
        af[r] = *(const bf16x8*)&As[row * 64 + (((s * 4 + quad) ^ (row & 7)) << 3)];
      }
#pragma unroll
      for (int c = 0; c < 4; ++c) {
        const int row = wc + c * 16 + l15;
        bf[c] = *(const bf16x8*)&Bs[row * 64 + (((s * 4 + quad) ^ (row & 7)) << 3)];
      }
#pragma unroll
      for (int r = 0; r < 4; ++r)
#pragma unroll
        for (int c = 0; c < 4; ++c)
          acc[r][c] = __builtin_amdgcn_mfma_f32_16x16x32_bf16(af[r], bf[c], acc[r][c], 0, 0, 0);
    }
  }

#pragma unroll
  for (int c = 0; c < 4; ++c) {
    const int col = n0 + wc + c * 16 + l15;
    const float bv = bias[col];
#pragma unroll
    for (int r = 0; r < 4; ++r) {
      const int row = m0 + wr + r * 16 + quad * 4;
#pragma unroll
      for (int i = 0; i < 4; ++i)
        C[(size_t)(row + i) * QKVROW + col] = f2bf(acc[r][c][i] + bv);
    }
  }
}

// ---------------------------------------------------------------------------
// In-place deinterleave+RoPE on q,k slots of qkv; Vt [b,h,hd,s] from v slot.
// q pre-scaled by hd^-0.5 * log2(e) so attn can use native exp2.
// ---------------------------------------------------------------------------
__global__ __launch_bounds__(256) void rope_vt(
    unsigned short* qkv, unsigned short* __restrict__ Vt,
    const float* __restrict__ tab) {
  __shared__ unsigned short vs[64 * 136];
  const int b = blockIdx.z, h = blockIdx.y, s0 = blockIdx.x * 64;
  const int tid = threadIdx.x;
  const int r = tid >> 2, cpart = (tid & 3) * 32;
  const int s = s0 + r;
  unsigned short* base = qkv + (size_t)(b * S_ + s) * QKVROW + h * 384;
  const int j0 = cpart >> 1;

  ushortx8 ivq[4], ivk[4], ivv[4];
#pragma unroll
  for (int i = 0; i < 4; ++i) {
    ivq[i] = *(const ushortx8*)&base[cpart + i * 8];
    ivk[i] = *(const ushortx8*)&base[128 + cpart + i * 8];
    ivv[i] = *(const ushortx8*)&base[256 + cpart + i * 8];
  }

  float cs[16], sn[16];
  {
    const f32x4* tr = (const f32x4*)&tab[(size_t)s * 128 + j0 * 2];
#pragma unroll
    for (int t = 0; t < 8; ++t) {
      const f32x4 v = tr[t];  // {cos,sin,cos,sin}
      cs[2 * t] = v[0]; sn[2 * t] = v[1];
      cs[2 * t + 1] = v[2]; sn[2 * t + 1] = v[3];
    }
  }

  __syncthreads();  // all reads of q/k rows done before anyone writes them

#pragma unroll
  for (int which = 0; which < 2; ++which) {
    const ushortx8* iv = (which == 0) ? ivq : ivk;
    // q: hd^-0.5 * log2(e)  (attn computes softmax with exp2)
    const float scale =
        (which == 0) ? (0.08838834764831845f * 1.4426950408889634f) : 1.0f;
    ushortx8 o1a, o1b, o2a, o2b;
#pragma unroll
    for (int t = 0; t < 16; ++t) {
      const float x1 = bf2f(iv[(2 * t) >> 3][(2 * t) & 7]);
      const float x2 = bf2f(iv[(2 * t + 1) >> 3][(2 * t + 1) & 7]);
      const unsigned short r1 = f2bf((x1 * cs[t] - x2 * sn[t]) * scale);
      const unsigned short r2 = f2bf((x2 * cs[t] + x1 * sn[t]) * scale);
      if (t < 8) { o1a[t] = r1; o2a[t] = r2; }
      else       { o1b[t - 8] = r1; o2b[t - 8] = r2; }
    }
    unsigned short* out = base + which * 128;
    *(ushortx8*)&out[j0] = o1a;
    *(ushortx8*)&out[j0 + 8] = o1b;
    *(ushortx8*)&out[64 + j0] = o2a;
    *(ushortx8*)&out[64 + j0 + 8] = o2b;
  }

#pragma unroll
  for (int i = 0; i < 4; ++i)
    *(ushortx8*)&vs[r * 136 + cpart + i * 8] = ivv[i];
  __syncthreads();
  const size_t vtb = (size_t)(b * H_ + h) * HD_ * S_ + s0;
#pragma unroll
  for (int it = 0; it < 4; ++it) {
    const int a = tid + it * 256;
    const int d = a >> 3, sc = (a & 7) * 8;
    ushortx8 o;
#pragma unroll
    for (int t = 0; t < 8; ++t) o[t] = vs[(sc + t) * 136 + d];
    *(ushortx8*)&Vt[vtb + (size_t)d * S_ + sc] = o;
  }
}

// ---------------------------------------------------------------------------
// Flash attention, causal. grid (32, 8, 2), 256 threads (4 waves).
// r10 single-buffer structure (r11 double-buffer regressed: occupancy 20->11).
// Round-12: lazy max-reduce -- per-lane max + wave __any test per tile;
// the exact 16-lane shfl reduce + rescale runs only on trigger (first tile
// and rare max growth), saving ~32 VALU ops/tile on this VALU-bound kernel.
// ---------------------------------------------------------------------------
__global__ __launch_bounds__(256) void attn(
    unsigned short* qkv, const unsigned short* __restrict__ Vt) {
  __shared__ unsigned short Ks[64 * 128];   // 16 KB, swizzled
  __shared__ unsigned short Vs[128 * 64];   // 16 KB, swizzled
  __shared__ unsigned short Ps[4 * 16 * 64];//  8 KB, swizzled per-wave strips
  const int bh = blockIdx.x, p = blockIdx.y, sub = blockIdx.z;
  const int b = bh >> 4, h = bh & 15;
  const int tid = threadIdx.x, lane = tid & 63, wave = tid >> 6;
  const int l15 = lane & 15, quad = lane >> 4;

  unsigned short* qh = qkv + (size_t)b * S_ * QKVROW + h * 384;
  const unsigned short* Vb = Vt + (size_t)bh * HD_ * S_;
  unsigned short* Pw = &Ps[wave * 16 * 64];

  ushortx8 rk[4], rv[4];
  auto pref = [&](int j) {  // stage kv-64 tile j into regs (256 threads)
#pragma unroll
    for (int t = 0; t < 4; ++t) {
      const int uk = t * 256 + tid;
      const int krow = uk >> 4, kcu = uk & 15;  // 64 rows x 16 units
      rk[t] = *(const ushortx8*)(qh + (size_t)(j * 64 + krow) * QKVROW + 128 + kcu * 8);
      const int vrow = uk >> 3, vcu = uk & 7;   // 128 rows x 8 units
      rv[t] = *(const ushortx8*)(Vb + (size_t)vrow * S_ + j * 64 + vcu * 8);
    }
  };
  pref(0);

#pragma unroll
  for (int half = 0; half < 2; ++half) {
    const int qt = half ? 15 - p : p;   // short tile first, then long
    const int jN = 2 * qt + 1 + sub;    // kv-64 tiles needed for this half-tile
    const int r0 = qt * 128 + sub * 64 + wave * 16;  // first q-row of this wave

    bf16x8 aq[4];
#pragma unroll
    for (int ks = 0; ks < 4; ++ks)
      aq[ks] = *(const bf16x8*)&qh[(size_t)(r0 + l15) * QKVROW + ks * 32 + quad * 8];

    f32x4 o[8];
    float mrow[4], lpart[4];
#pragma unroll
    for (int ct = 0; ct < 8; ++ct) o[ct] = (f32x4){0.f, 0.f, 0.f, 0.f};
#pragma unroll
    for (int i = 0; i < 4; ++i) { mrow[i] = -1e30f; lpart[i] = 0.f; }

    for (int j = 0; j < jN; ++j) {
      __syncthreads();  // all waves done reading Ks/Vs of previous tile
#pragma unroll
      for (int t = 0; t < 4; ++t) {
        const int uk = t * 256 + tid;
        const int krow = uk >> 4, kun = uk & 15;
        *(ushortx8*)&Ks[krow * 128 + ((kun ^ (krow & 7)) << 3)] = rk[t];
        const int vrow = uk >> 3, vun = uk & 7;
        *(ushortx8*)&Vs[vrow * 64 + ((vun ^ (vrow & 7)) << 3)] = rv[t];
      }
      __syncthreads();  // tiles visible

      const int jn = (j + 1 < jN) ? j + 1 : (half == 0 ? 0 : -1);
      if (jn >= 0) pref(jn);  // overlaps MFMA/softmax below

      // S = Q K^T over this kv-64 tile (Q pre-scaled by hd^-0.5*log2e)
      f32x4 sacc[4];
#pragma unroll
      for (int ct = 0; ct < 4; ++ct) sacc[ct] = (f32x4){0.f, 0.f, 0.f, 0.f};
      __builtin_amdgcn_s_setprio(1);
#pragma unroll
      for (int ks = 0; ks < 4; ++ks) {
        bf16x8 bk[4];
#pragma unroll
        for (int ct = 0; ct < 4; ++ct)
          bk[ct] = *(const bf16x8*)&Ks[(ct * 16 + l15) * 128 +
                                       (((ks * 4 + quad) ^ (l15 & 7)) << 3)];
#pragma unroll
        for (int ct = 0; ct < 4; ++ct)
          sacc[ct] = __builtin_amdgcn_mfma_f32_16x16x32_bf16(aq[ks], bk[ct], sacc[ct], 0, 0, 0);
      }
      __builtin_amdgcn_s_setprio(0);

      if (j >= 2 * qt) {  // diagonal region: mask gcol > grow
#pragma unroll
        for (int ct = 0; ct < 4; ++ct)
#pragma unroll
          for (int i = 0; i < 4; ++i) {
            const int grow = r0 + quad * 4 + i;
            const int gcol = j * 64 + ct * 16 + l15;
            if (gcol > grow) sacc[ct][i] = -1e30f;
          }
      }

      // lazy max: per-lane max only; exact reduce just on trigger
      float lmax[4];
#pragma unroll
      for (int i = 0; i < 4; ++i)
        lmax[i] = fmaxf(fmaxf(sacc[0][i], sacc[1][i]), fmaxf(sacc[2][i], sacc[3][i]));
      bool need = false;
#pragma unroll
      for (int i = 0; i < 4; ++i) need = need || (lmax[i] > mrow[i] + 8.f);
      if (__any(need)) {
#pragma unroll
        for (int i = 0; i < 4; ++i) {
          float m = lmax[i];
#pragma unroll
          for (int off = 1; off < 16; off <<= 1) m = fmaxf(m, __shfl_xor(m, off));
          const float mn = fmaxf(mrow[i], m);
          const float alpha = exp2f(mrow[i] - mn);
          mrow[i] = mn;
          lpart[i] *= alpha;
#pragma unroll
          for (int ct = 0; ct < 8; ++ct) o[ct][i] *= alpha;
        }
      }
      // P = exp2(S - mrow), bounded by 2^8; per-lane partial row sums
#pragma unroll
      for (int i = 0; i < 4; ++i) {
        float rs = 0.f;
#pragma unroll
        for (int ct = 0; ct < 4; ++ct) {
          const float pv = exp2f(sacc[ct][i] - mrow[i]);
          sacc[ct][i] = pv;
          rs += pv;
        }
        lpart[i] += rs;
      }

      // P into wave-private swizzled strip (C-layout -> A-layout)
#pragma unroll
      for (int ct = 0; ct < 4; ++ct)
#pragma unroll
        for (int i = 0; i < 4; ++i) {
          const int row = quad * 4 + i;
          const int u = ct * 2 + (l15 >> 3);
          Pw[row * 64 + ((u ^ (row & 7)) << 3) + (l15 & 7)] = f2bf(sacc[ct][i]);
        }

      // O += P * V
      __builtin_amdgcn_s_setprio(1);
#pragma unroll
      for (int ks = 0; ks < 2; ++ks) {
        const bf16x8 ap = *(const bf16x8*)&Pw[l15 * 64 +
                                              (((ks * 4 + quad) ^ (l15 & 7)) << 3)];
        bf16x8 bv[8];
#pragma unroll
        for (int ct = 0; ct < 8; ++ct)
          bv[ct] = *(const bf16x8*)&Vs[(ct * 16 + l15) * 64 +
                                       (((ks * 4 + quad) ^ (l15 & 7)) << 3)];
#pragma unroll
        for (int ct = 0; ct < 8; ++ct)
          o[ct] = __builtin_amdgcn_mfma_f32_16x16x32_bf16(ap, bv[ct], o[ct], 0, 0, 0);
      }
      __builtin_amdgcn_s_setprio(0);
    }

    // final 16-lane sum reduction (once per q-tile), then write ctx
    float inv[4];
#pragma unroll
    for (int i = 0; i < 4; ++i) {
      float l = lpart[i];
#pragma unroll
      for (int off = 1; off < 16; off <<= 1) l += __shfl_xor(l, off);
      inv[i] = 1.0f / l;
    }
#pragma unroll
    for (int ct = 0; ct < 8; ++ct)
#pragma unroll
      for (int i = 0; i < 4; ++i) {
        const int srow = r0 + quad * 4 + i;
        qh[(size_t)srow * QKVROW + ct * 16 + l15] = f2bf(o[ct][i] * inv[i]);
      }
  }
}

// ---------------------------------------------------------------------------
// GEMM2: out[m,n] = sum_k ctx[m,k]*wob[n,k] + bo[n].  Both operands bf16,
// both staged via global_load_lds with rule-21 swizzle. (Verified.)
// ---------------------------------------------------------------------------
__global__ __launch_bounds__(256) void gemm2(
    const unsigned short* __restrict__ A, const unsigned short* __restrict__ Bm,
    const float* __restrict__ bias, float* __restrict__ C) {
  __shared__ unsigned short As[128 * 64];
  __shared__ unsigned short Bs[128 * 64];
  const int tid = threadIdx.x;
  const int lane = tid & 63, wave = tid >> 6;
  const int l15 = lane & 15, quad = lane >> 4;
  const int m0 = blockIdx.y * 128, n0 = blockIdx.x * 128;
  const int wr = (wave >> 1) * 64, wc = (wave & 1) * 64;

  f32x4 acc[4][4];
#pragma unroll
  for (int r = 0; r < 4; ++r)
#pragma unroll
    for (int c = 0; c < 4; ++c) acc[r][c] = (f32x4){0.f, 0.f, 0.f, 0.f};

  for (int k0 = 0; k0 < 2048; k0 += 64) {
    const int kh = ((k0 >> 7) * 384) + (k0 & 127);  // ctx lives in q slots
    __syncthreads();  // prior frag reads done
#pragma unroll
    for (int i = 0; i < 4; ++i) {
      const int c0 = wave * 256 + i * 64;
      const int u = c0 + lane;
      const int row = u >> 3, cu = u & 7;
      const int cs = cu ^ (row & 7);        // pre-swizzled source column
      async16(A + (size_t)(m0 + row) * QKVROW + kh + cs * 8, &As[c0 * 8]);
      async16(Bm + (size_t)(n0 + row) * 2048 + k0 + cs * 8, &Bs[c0 * 8]);
    }
    __syncthreads();  // drains vmcnt -> tiles visible

#pragma unroll
    for (int s = 0; s < 2; ++s) {
      bf16x8 af[4], bf[4];
#pragma unroll
      for (int r = 0; r < 4; ++r) {
        const int row = wr + r * 16 + l15;
        af[r] = *(const bf16x8*)&As[row * 64 + (((s * 4 + quad) ^ (row & 7)) << 3)];
      }
#pragma unroll
      for (int c = 0; c < 4; ++c) {
        const int row = wc + c * 16 + l15;
        bf[c] = *(const bf16x8*)&Bs[row * 64 + (((s * 4 + quad) ^ (row & 7)) << 3)];
      }
#pragma unroll
      for (int r = 0; r < 4; ++r)
#pragma unroll
        for (int c = 0; c < 4; ++c)
          acc[r][c] = __builtin_amdgcn_mfma_f32_16x16x32_bf16(af[r], bf[c], acc[r][c], 0, 0, 0);
    }
  }

#pragma unroll
  for (int c = 0; c < 4; ++c) {
    const int col = n0 + wc + c * 16 + l15;
    const float bv = bias[col];
#pragma unroll
    for (int r = 0; r < 4; ++r) {
      const int row = m0 + wr + r * 16 + quad * 4;
#pragma unroll
      for (int i = 0; i < 4; ++i)
        C[(size_t)(row + i) * 2048 + col] = acc[r][c][i] + bv;
    }
  }
}

extern "C" void kernel_launch(void* const* d_in, const int* in_sizes, int n_in,
                              void* d_out, int out_size, void* d_ws, size_t ws_size,
                              hipStream_t stream) {
  const float* x    = (const float*)d_in[0];
  const float* wqkv = (const float*)d_in[1];
  const float* bqkv = (const float*)d_in[2];
  const float* wo   = (const float*)d_in[3];
  const float* bo   = (const float*)d_in[4];
  float* out = (float*)d_out;

  unsigned short* qkv = (unsigned short*)d_ws;            // 50.3 MB [4096][6144]
  unsigned short* Vt  = qkv + (size_t)M_ * QKVROW;        // 16.8 MB [b,h,hd,s]
  unsigned short* xb  = Vt  + (size_t)B_ * H_ * HD_ * S_; // 16.8 MB [4096][2048] bf16
  unsigned short* wb  = xb  + (size_t)M_ * 2048;          // 25.2 MB [6144][2048] bf16
  unsigned short* wob = wb  + (size_t)QKVROW * 2048;      //  8.4 MB [2048][2048] bf16
  float* tab = (float*)(wob + (size_t)2048 * 2048);       //  1.0 MB [2048][64][2]

  f2bf3t<<<dim3(2048), 256, 0, stream>>>(x, xb, (M_ * 2048) / 8,
                                         wqkv, wb, (QKVROW * 2048) / 8,
                                         wo, wob, (2048 * 2048) / 8,
                                         tab, (S_ * 128) / 8);

  gemm1<<<dim3(QKVROW / 128, M_ / 128), 256, 0, stream>>>(xb, wb, bqkv, qkv);
  rope_vt<<<dim3(S_ / 64, H_, B_), 256, 0, stream>>>(qkv, Vt, tab);
  attn<<<dim3(B_ * H_, 8, 2), 256, 0, stream>>>(qkv, Vt);
  gemm2<<<dim3(2048 / 128, M_ / 128), 256, 0, stream>>>(qkv, wob, bo, out);
}

// Round 13
// 403.236 us; speedup vs baseline: 1.1159x; 1.0134x over previous
//
#include <hip/hip_runtime.h>

#define B_ 2
#define S_ 2048
#define H_ 16
#define HD_ 128
#define QKVROW 6144   // 3*2048, row length of qkv activation
#define M_ 4096       // B_*S_

typedef float f32x4 __attribute__((ext_vector_type(4)));
typedef __bf16 bf16x8 __attribute__((ext_vector_type(8)));
typedef unsigned short ushortx8 __attribute__((ext_vector_type(8)));

__device__ __forceinline__ float bf2f(unsigned short u) {
  union { unsigned u; float f; } v;
  v.u = ((unsigned)u) << 16;
  return v.f;
}
__device__ __forceinline__ unsigned short f2bf(float f) {
  union { __bf16 b; unsigned short u; } c;
  c.b = (__bf16)f;  // native v_cvt path
  return c.u;
}
// 8 contiguous fp32 -> 8 bf16 ushorts (vector loads + native cvt)
__device__ __forceinline__ ushortx8 cvt8(const float* f) {
  const f32x4 lo = *(const f32x4*)f;
  const f32x4 hi = *(const f32x4*)(f + 4);
  ushortx8 o;
#pragma unroll
  for (int t = 0; t < 4; ++t) o[t] = f2bf(lo[t]);
#pragma unroll
  for (int t = 0; t < 4; ++t) o[4 + t] = f2bf(hi[t]);
  return o;
}
// async global->LDS, 16B/lane. LDS dest = wave-uniform base + lane*16.
__device__ __forceinline__ void async16(const unsigned short* g, unsigned short* l) {
  __builtin_amdgcn_global_load_lds(
      (const __attribute__((address_space(1))) unsigned int*)g,
      (__attribute__((address_space(3))) unsigned int*)l, 16, 0, 0);
}

// ---------------------------------------------------------------------------
// One-time RoPE cos/sin table: tab[s][j] = {cos, sin}(s * base^(-j/64)).
// ---------------------------------------------------------------------------
__global__ __launch_bounds__(256) void rope_table(float* __restrict__ tab) {
  const int i = blockIdx.x * 256 + threadIdx.x;  // [0, 2048*64)
  const int s = i >> 6, t = i & 63;
  const float invf = expf(-(float)t * 0.14391156831212787f);  // ln(1e4)/64
  float sn, cs;
  sincosf((float)s * invf, &sn, &cs);
  tab[2 * i] = cs;
  tab[2 * i + 1] = sn;
}

// ---------------------------------------------------------------------------
// One-time fp32 -> bf16 conversion of x, Wqkv, wo in a single launch.
// ---------------------------------------------------------------------------
__global__ __launch_bounds__(256) void f2bf3(
    const float* __restrict__ a, unsigned short* __restrict__ da, int na8,
    const float* __restrict__ b, unsigned short* __restrict__ db, int nb8,
    const float* __restrict__ c, unsigned short* __restrict__ dc, int nc8) {
  const int ntot = na8 + nb8 + nc8;
  int i = blockIdx.x * 256 + threadIdx.x;
  const int stride = gridDim.x * 256;
  for (; i < ntot; i += stride) {
    const float* s;
    unsigned short* d;
    int off = i;
    if (off < na8) { s = a; d = da; }
    else if (off - na8 < nb8) { off -= na8; s = b; d = db; }
    else { off -= na8 + nb8; s = c; d = dc; }
    const ushortx8 o = cvt8(s + (size_t)off * 8);
    *(ushortx8*)&d[(size_t)off * 8] = o;
  }
}

// ---------------------------------------------------------------------------
// GEMM1: qkv[m,n] = sum_k xb[m,k]*wb[n,k] + b[n].  xb,wb bf16; C bf16.
// m97 structure + rule-21 swizzle (verified: ~130 us, MfmaUtil ~34%,
// 0 bank conflicts). Pipelining attempts (r3 coarse 8-phase, r5 2-deep
// counted vmcnt) both regressed -- this 2-barrier schedule is the
// structure's sweet spot.
// ---------------------------------------------------------------------------
__global__ __launch_bounds__(256) void gemm1(
    const unsigned short* __restrict__ A, const unsigned short* __restrict__ Bm,
    const float* __restrict__ bias, unsigned short* __restrict__ C) {
  __shared__ unsigned short As[128 * 64];
  __shared__ unsigned short Bs[128 * 64];
  const int tid = threadIdx.x;
  const int lane = tid & 63, wave = tid >> 6;
  const int l15 = lane & 15, quad = lane >> 4;
  const int m0 = blockIdx.y * 128, n0 = blockIdx.x * 128;
  const int wr = (wave >> 1) * 64, wc = (wave & 1) * 64;

  f32x4 acc[4][4];
#pragma unroll
  for (int r = 0; r < 4; ++r)
#pragma unroll
    for (int c = 0; c < 4; ++c) acc[r][c] = (f32x4){0.f, 0.f, 0.f, 0.f};

  for (int k0 = 0; k0 < 2048; k0 += 64) {
    __syncthreads();  // prior iteration's frag reads done
#pragma unroll
    for (int i = 0; i < 4; ++i) {
      const int c0 = wave * 256 + i * 64;   // 16B-unit base within tile
      const int u = c0 + lane;
      const int row = u >> 3, cu = u & 7;   // 128 rows x 8 units
      const int cs = cu ^ (row & 7);        // pre-swizzled source column
      async16(A + (size_t)(m0 + row) * 2048 + k0 + cs * 8, &As[c0 * 8]);
      async16(Bm + (size_t)(n0 + row) * 2048 + k0 + cs * 8, &Bs[c0 * 8]);
    }
    __syncthreads();  // drains vmcnt -> tiles visible

#pragma unroll
    for (int s = 0; s < 2; ++s) {
      bf16x8 af[4], bf[4];
#pragma unroll
      for (int r = 0; r < 4; ++r) {
        const int row = wr + r * 16 + l15;
        af[r] = *(const bf16x8*)&As[row * 64 + (((s * 4 + quad) ^ (row & 7)) << 3)];
      }
#pragma unroll
      for (int c = 0; c < 4; ++c) {
        const int row = wc + c * 16 + l15;
        bf[c] = *(const bf16x8*)&Bs[row * 64 + (((s * 4 + quad) ^ (row & 7)) << 3)];
      }
#pragma unroll
      for (int r = 0; r < 4; ++r)
#pragma unroll
        for (int c = 0; c < 4; ++c)
          acc[r][c] = __builtin_amdgcn_mfma_f32_16x16x32_bf16(af[r], bf[c], acc[r][c], 0, 0, 0);
    }
  }

#pragma unroll
  for (int c = 0; c < 4; ++c) {
    const int col = n0 + wc + c * 16 + l15;
    const float bv = bias[col];
#pragma unroll
    for (int r = 0; r < 4; ++r) {
      const int row = m0 + wr + r * 16 + quad * 4;
#pragma unroll
      for (int i = 0; i < 4; ++i)
        C[(size_t)(row + i) * QKVROW + col] = f2bf(acc[r][c][i] + bv);
    }
  }
}

// ---------------------------------------------------------------------------
// In-place deinterleave+RoPE on q,k slots of qkv (q pre-scaled by hd^-0.5);
// Vt [b,h,hd,s] from the v slot. Trig from the precomputed table.
// ---------------------------------------------------------------------------
__global__ __launch_bounds__(256) void rope_vt(
    unsigned short* qkv, unsigned short* __restrict__ Vt,
    const float* __restrict__ tab) {
  __shared__ unsigned short vs[64 * 136];
  const int b = blockIdx.z, h = blockIdx.y, s0 = blockIdx.x * 64;
  const int tid = threadIdx.x;
  const int r = tid >> 2, cpart = (tid & 3) * 32;
  const int s = s0 + r;
  unsigned short* base = qkv + (size_t)(b * S_ + s) * QKVROW + h * 384;
  const int j0 = cpart >> 1;

  ushortx8 ivq[4], ivk[4], ivv[4];
#pragma unroll
  for (int i = 0; i < 4; ++i) {
    ivq[i] = *(const ushortx8*)&base[cpart + i * 8];
    ivk[i] = *(const ushortx8*)&base[128 + cpart + i * 8];
    ivv[i] = *(const ushortx8*)&base[256 + cpart + i * 8];
  }

  float cs[16], sn[16];
  {
    const f32x4* tr = (const f32x4*)&tab[(size_t)s * 128 + j0 * 2];
#pragma unroll
    for (int t = 0; t < 8; ++t) {
      const f32x4 v = tr[t];  // {cos,sin,cos,sin}
      cs[2 * t] = v[0]; sn[2 * t] = v[1];
      cs[2 * t + 1] = v[2]; sn[2 * t + 1] = v[3];
    }
  }

  __syncthreads();  // all reads of q/k rows done before anyone writes them

#pragma unroll
  for (int which = 0; which < 2; ++which) {
    const ushortx8* iv = (which == 0) ? ivq : ivk;
    const float scale = (which == 0) ? 0.08838834764831845f : 1.0f;
    ushortx8 o1a, o1b, o2a, o2b;
#pragma unroll
    for (int t = 0; t < 16; ++t) {
      const float x1 = bf2f(iv[(2 * t) >> 3][(2 * t) & 7]);
      const float x2 = bf2f(iv[(2 * t + 1) >> 3][(2 * t + 1) & 7]);
      const unsigned short r1 = f2bf((x1 * cs[t] - x2 * sn[t]) * scale);
      const unsigned short r2 = f2bf((x2 * cs[t] + x1 * sn[t]) * scale);
      if (t < 8) { o1a[t] = r1; o2a[t] = r2; }
      else       { o1b[t - 8] = r1; o2b[t - 8] = r2; }
    }
    unsigned short* out = base + which * 128;
    *(ushortx8*)&out[j0] = o1a;
    *(ushortx8*)&out[j0 + 8] = o1b;
    *(ushortx8*)&out[64 + j0] = o2a;
    *(ushortx8*)&out[64 + j0 + 8] = o2b;
  }

#pragma unroll
  for (int i = 0; i < 4; ++i)
    *(ushortx8*)&vs[r * 136 + cpart + i * 8] = ivv[i];
  __syncthreads();
  const size_t vtb = (size_t)(b * H_ + h) * HD_ * S_ + s0;
#pragma unroll
  for (int it = 0; it < 4; ++it) {
    const int a = tid + it * 256;
    const int d = a >> 3, sc = (a & 7) * 8;
    ushortx8 o;
#pragma unroll
    for (int t = 0; t < 8; ++t) o[t] = vs[(sc + t) * 136 + d];
    *(ushortx8*)&Vt[vtb + (size_t)d * S_ + sc] = o;
  }
}

// ---------------------------------------------------------------------------
// Flash attention v3, causal. grid (32, 8, 2), 256 threads (4 waves).
// Champion configuration (402.6 us total, round 7):
//  * bh = blockIdx.x: the 16 blocks sharing one head's K/V have linear-id
//    stride 32 (== 0 mod 8 XCDs) -> same XCD; 4 bh x 1MB K/V fits its L2.
//  * deferred-sum softmax: lrow kept as per-lane partial (alpha uniform per
//    16-lane row group), 16-lane sum reduction once per q-tile.
//  * defer-max (T13, THR=8): skip o-rescale pass when max growth bounded.
//  * s_setprio(1) around QK^T and PV MFMA clusters (T5).
// Later variants (LDS swizzle/exp2 r10, lazy-max r12, double-buffer r11)
// measured neutral or negative; this is the best verified state.
// ---------------------------------------------------------------------------
__global__ __launch_bounds__(256) void attn(
    unsigned short* qkv, const unsigned short* __restrict__ Vt) {
  __shared__ unsigned short Ks[64 * 136];   // 17.4 KB
  __shared__ unsigned short Vs[128 * 72];   // 18.4 KB
  __shared__ unsigned short Ps[4 * 16 * 72];//  9.2 KB (per-wave strips)
  const int bh = blockIdx.x, p = blockIdx.y, sub = blockIdx.z;
  const int b = bh >> 4, h = bh & 15;
  const int tid = threadIdx.x, lane = tid & 63, wave = tid >> 6;
  const int l15 = lane & 15, quad = lane >> 4;

  unsigned short* qh = qkv + (size_t)b * S_ * QKVROW + h * 384;
  const unsigned short* Vb = Vt + (size_t)bh * HD_ * S_;
  unsigned short* Pw = &Ps[wave * 16 * 72];

  ushortx8 rk[4], rv[4];
  auto pref = [&](int j) {  // stage kv-64 tile j into regs (256 threads)
#pragma unroll
    for (int t = 0; t < 4; ++t) {
      const int uk = t * 256 + tid;
      const int krow = uk >> 4, kcu = uk & 15;  // 64 rows x 16 units
      rk[t] = *(const ushortx8*)(qh + (size_t)(j * 64 + krow) * QKVROW + 128 + kcu * 8);
      const int vrow = uk >> 3, vcu = uk & 7;   // 128 rows x 8 units
      rv[t] = *(const ushortx8*)(Vb + (size_t)vrow * S_ + j * 64 + vcu * 8);
    }
  };
  pref(0);

#pragma unroll
  for (int half = 0; half < 2; ++half) {
    const int qt = half ? 15 - p : p;   // short tile first, then long
    const int jN = 2 * qt + 1 + sub;    // kv-64 tiles needed for this half-tile
    const int r0 = qt * 128 + sub * 64 + wave * 16;  // first q-row of this wave

    bf16x8 aq[4];
#pragma unroll
    for (int ks = 0; ks < 4; ++ks)
      aq[ks] = *(const bf16x8*)&qh[(size_t)(r0 + l15) * QKVROW + ks * 32 + quad * 8];

    f32x4 o[8];
    float mrow[4], lpart[4];
#pragma unroll
    for (int ct = 0; ct < 8; ++ct) o[ct] = (f32x4){0.f, 0.f, 0.f, 0.f};
#pragma unroll
    for (int i = 0; i < 4; ++i) { mrow[i] = -1e30f; lpart[i] = 0.f; }

    for (int j = 0; j < jN; ++j) {
      __syncthreads();  // all waves done reading Ks/Vs of previous tile
#pragma unroll
      for (int t = 0; t < 4; ++t) {
        const int uk = t * 256 + tid;
        *(ushortx8*)&Ks[(uk >> 4) * 136 + (uk & 15) * 8] = rk[t];
        *(ushortx8*)&Vs[(uk >> 3) * 72 + (uk & 7) * 8] = rv[t];
      }
      __syncthreads();  // tiles visible

      const int jn = (j + 1 < jN) ? j + 1 : (half == 0 ? 0 : -1);
      if (jn >= 0) pref(jn);  // overlaps MFMA/softmax below

      // S = Q K^T over this kv-64 tile (Q pre-scaled by hd^-0.5)
      f32x4 sacc[4];
#pragma unroll
      for (int ct = 0; ct < 4; ++ct) sacc[ct] = (f32x4){0.f, 0.f, 0.f, 0.f};
      __builtin_amdgcn_s_setprio(1);
#pragma unroll
      for (int ks = 0; ks < 4; ++ks) {
        bf16x8 bk[4];
#pragma unroll
        for (int ct = 0; ct < 4; ++ct)
          bk[ct] = *(const bf16x8*)&Ks[(ct * 16 + l15) * 136 + ks * 32 + quad * 8];
#pragma unroll
        for (int ct = 0; ct < 4; ++ct)
          sacc[ct] = __builtin_amdgcn_mfma_f32_16x16x32_bf16(aq[ks], bk[ct], sacc[ct], 0, 0, 0);
      }
      __builtin_amdgcn_s_setprio(0);

      if (j >= 2 * qt) {  // diagonal region: mask gcol > grow
#pragma unroll
        for (int ct = 0; ct < 4; ++ct)
#pragma unroll
          for (int i = 0; i < 4; ++i) {
            const int grow = r0 + quad * 4 + i;
            const int gcol = j * 64 + ct * 16 + l15;
            if (gcol > grow) sacc[ct][i] = -1e30f;
          }
      }

      // per-row tile max (uniform within each 16-lane row group after reduce)
      float tmax[4];
#pragma unroll
      for (int i = 0; i < 4; ++i) {
        float m = fmaxf(fmaxf(sacc[0][i], sacc[1][i]), fmaxf(sacc[2][i], sacc[3][i]));
#pragma unroll
        for (int off = 1; off < 16; off <<= 1) m = fmaxf(m, __shfl_xor(m, off));
        tmax[i] = m;
      }
      // defer-max: only rescale when some row's max grew past THR=8
      bool need = false;
#pragma unroll
      for (int i = 0; i < 4; ++i) need = need || (tmax[i] > mrow[i] + 8.f);
      if (__any(need)) {
#pragma unroll
        for (int i = 0; i < 4; ++i) {
          const float mn = fmaxf(mrow[i], tmax[i]);
          const float alpha = __expf(mrow[i] - mn);
          mrow[i] = mn;
          lpart[i] *= alpha;
#pragma unroll
          for (int ct = 0; ct < 8; ++ct) o[ct][i] *= alpha;
        }
      }
      // P = exp(S - mrow); accumulate per-lane partial row sums
#pragma unroll
      for (int i = 0; i < 4; ++i) {
        float rs = 0.f;
#pragma unroll
        for (int ct = 0; ct < 4; ++ct) {
          const float pv = __expf(sacc[ct][i] - mrow[i]);
          sacc[ct][i] = pv;
          rs += pv;
        }
        lpart[i] += rs;
      }

      // P into wave-private strip (C-layout -> A-layout); no barrier needed
#pragma unroll
      for (int ct = 0; ct < 4; ++ct)
#pragma unroll
        for (int i = 0; i < 4; ++i)
          Pw[(quad * 4 + i) * 72 + ct * 16 + l15] = f2bf(sacc[ct][i]);

      // O += P * V
      __builtin_amdgcn_s_setprio(1);
#pragma unroll
      for (int ks = 0; ks < 2; ++ks) {
        const bf16x8 ap = *(const bf16x8*)&Pw[l15 * 72 + ks * 32 + quad * 8];
        bf16x8 bv[8];
#pragma unroll
        for (int ct = 0; ct < 8; ++ct)
          bv[ct] = *(const bf16x8*)&Vs[(ct * 16 + l15) * 72 + ks * 32 + quad * 8];
#pragma unroll
        for (int ct = 0; ct < 8; ++ct)
          o[ct] = __builtin_amdgcn_mfma_f32_16x16x32_bf16(ap, bv[ct], o[ct], 0, 0, 0);
      }
      __builtin_amdgcn_s_setprio(0);
    }

    // final 16-lane sum reduction (once per q-tile), then write ctx
    float inv[4];
#pragma unroll
    for (int i = 0; i < 4; ++i) {
      float l = lpart[i];
#pragma unroll
      for (int off = 1; off < 16; off <<= 1) l += __shfl_xor(l, off);
      inv[i] = 1.0f / l;
    }
#pragma unroll
    for (int ct = 0; ct < 8; ++ct)
#pragma unroll
      for (int i = 0; i < 4; ++i) {
        const int srow = r0 + quad * 4 + i;
        qh[(size_t)srow * QKVROW + ct * 16 + l15] = f2bf(o[ct][i] * inv[i]);
      }
  }
}

// ---------------------------------------------------------------------------
// GEMM2: out[m,n] = sum_k ctx[m,k]*wob[n,k] + bo[n].  Both operands bf16,
// both staged via global_load_lds with rule-21 swizzle. (Verified.)
// ---------------------------------------------------------------------------
__global__ __launch_bounds__(256) void gemm2(
    const unsigned short* __restrict__ A, const unsigned short* __restrict__ Bm,
    const float* __restrict__ bias, float* __restrict__ C) {
  __shared__ unsigned short As[128 * 64];
  __shared__ unsigned short Bs[128 * 64];
  const int tid = threadIdx.x;
  const int lane = tid & 63, wave = tid >> 6;
  const int l15 = lane & 15, quad = lane >> 4;
  const int m0 = blockIdx.y * 128, n0 = blockIdx.x * 128;
  const int wr = (wave >> 1) * 64, wc = (wave & 1) * 64;

  f32x4 acc[4][4];
#pragma unroll
  for (int r = 0; r < 4; ++r)
#pragma unroll
    for (int c = 0; c < 4; ++c) acc[r][c] = (f32x4){0.f, 0.f, 0.f, 0.f};

  for (int k0 = 0; k0 < 2048; k0 += 64) {
    const int kh = ((k0 >> 7) * 384) + (k0 & 127);  // ctx lives in q slots
    __syncthreads();  // prior frag reads done
#pragma unroll
    for (int i = 0; i < 4; ++i) {
      const int c0 = wave * 256 + i * 64;
      const int u = c0 + lane;
      const int row = u >> 3, cu = u & 7;
      const int cs = cu ^ (row & 7);        // pre-swizzled source column
      async16(A + (size_t)(m0 + row) * QKVROW + kh + cs * 8, &As[c0 * 8]);
      async16(Bm + (size_t)(n0 + row) * 2048 + k0 + cs * 8, &Bs[c0 * 8]);
    }
    __syncthreads();  // drains vmcnt -> tiles visible

#pragma unroll
    for (int s = 0; s < 2; ++s) {
      bf16x8 af[4], bf[4];
#pragma unroll
      for (int r = 0; r < 4; ++r) {
        const int row = wr + r * 16 + l15;
        af[r] = *(const bf16x8*)&As[row * 64 + (((s * 4 + quad) ^ (row & 7)) << 3)];
      }
#pragma unroll
      for (int c = 0; c < 4; ++c) {
        const int row = wc + c * 16 + l15;
        bf[c] = *(const bf16x8*)&Bs[row * 64 + (((s * 4 + quad) ^ (row & 7)) << 3)];
      }
#pragma unroll
      for (int r = 0; r < 4; ++r)
#pragma unroll
        for (int c = 0; c < 4; ++c)
          acc[r][c] = __builtin_amdgcn_mfma_f32_16x16x32_bf16(af[r], bf[c], acc[r][c], 0, 0, 0);
    }
  }

#pragma unroll
  for (int c = 0; c < 4; ++c) {
    const int col = n0 + wc + c * 16 + l15;
    const float bv = bias[col];
#pragma unroll
    for (int r = 0; r < 4; ++r) {
      const int row = m0 + wr + r * 16 + quad * 4;
#pragma unroll
      for (int i = 0; i < 4; ++i)
        C[(size_t)(row + i) * 2048 + col] = acc[r][c][i] + bv;
    }
  }
}

extern "C" void kernel_launch(void* const* d_in, const int* in_sizes, int n_in,
                              void* d_out, int out_size, void* d_ws, size_t ws_size,
                              hipStream_t stream) {
  const float* x    = (const float*)d_in[0];
  const float* wqkv = (const float*)d_in[1];
  const float* bqkv = (const float*)d_in[2];
  const float* wo   = (const float*)d_in[3];
  const float* bo   = (const float*)d_in[4];
  float* out = (float*)d_out;

  unsigned short* qkv = (unsigned short*)d_ws;            // 50.3 MB [4096][6144]
  unsigned short* Vt  = qkv + (size_t)M_ * QKVROW;        // 16.8 MB [b,h,hd,s]
  unsigned short* xb  = Vt  + (size_t)B_ * H_ * HD_ * S_; // 16.8 MB [4096][2048] bf16
  unsigned short* wb  = xb  + (size_t)M_ * 2048;          // 25.2 MB [6144][2048] bf16
  unsigned short* wob = wb  + (size_t)QKVROW * 2048;      //  8.4 MB [2048][2048] bf16
  float* tab = (float*)(wob + (size_t)2048 * 2048);       //  1.0 MB [2048][64][2]

  rope_table<<<dim3((S_ * 64) / 256), 256, 0, stream>>>(tab);
  f2bf3<<<dim3(2048), 256, 0, stream>>>(x, xb, (M_ * 2048) / 8,
                                        wqkv, wb, (QKVROW * 2048) / 8,
                                        wo, wob, (2048 * 2048) / 8);

  gemm1<<<dim3(QKVROW / 128, M_ / 128), 256, 0, stream>>>(xb, wb, bqkv, qkv);
  rope_vt<<<dim3(S_ / 64, H_, B_), 256, 0, stream>>>(qkv, Vt, tab);
  attn<<<dim3(B_ * H_, 8, 2), 256, 0, stream>>>(qkv, Vt);
  gemm2<<<dim3(2048 / 128, M_ / 128), 256, 0, stream>>>(qkv, wob, bo, out);
}